// Round 1
// 2189.005 us; speedup vs baseline: 1.0468x; 1.0468x over previous
//
#include <hip/hip_runtime.h>

typedef unsigned short u16;
typedef unsigned int u32;

#define NN 50000
#define NE 150000
#define D 42
#define EH 128
#define DD 1764   // D*D
#define STEPS 6
#define MS 48     // msg row stride (floats), 192 B = 16B-aligned

typedef __attribute__((ext_vector_type(8))) short bf8;
typedef __attribute__((ext_vector_type(4))) float f4;

static __device__ __forceinline__ float bf2f(u16 v) {
  return __uint_as_float(((u32)v) << 16);
}
static __device__ __forceinline__ u16 f2bf(float f) {
  u32 x = __float_as_uint(f);
  return (u16)((x + 0x7fffu + ((x >> 16) & 1u)) >> 16);  // RNE
}

// ---------------------------------------------------------------------------
// Dtype probe (bf16 vs fp32 inputs).
// ---------------------------------------------------------------------------
__global__ void k_detect(const u32* __restrict__ words, int* __restrict__ flag) {
  __shared__ int cnt;
  if (threadIdx.x == 0) cnt = 0;
  __syncthreads();
  int bad = 0;
  for (int i = threadIdx.x; i < 4096; i += 256) {
    u32 w = words[i];
    float v = __uint_as_float((w & 0xffffu) << 16);
    float a = fabsf(v);
    if (!(a < 16.0f)) bad++;
  }
  if (bad) atomicAdd(&cnt, bad);
  __syncthreads();
  if (threadIdx.x == 0) flag[0] = (cnt < 100) ? 1 : 0;
}

__global__ void k_cvt(const void* __restrict__ src, float* __restrict__ dst,
                      int count, const int* __restrict__ flag) {
  int i = blockIdx.x * blockDim.x + threadIdx.x;
  if (i >= count) return;
  if (flag[0]) dst[i] = bf2f(((const u16*)src)[i]);
  else         dst[i] = ((const float*)src)[i];
}

// ---------------------------------------------------------------------------
// CSR build: histogram of dst, block-scan to row starts, rank assignment.
// dst is constant across the 6 steps so this is once per launch.
// ---------------------------------------------------------------------------
__global__ void k_hist(const int* __restrict__ dstI, int* __restrict__ cnt) {
  int e = blockIdx.x * blockDim.x + threadIdx.x;
  if (e < NE) atomicAdd(&cnt[dstI[e]], 1);
}

// Single-block running scan: rs[0]=0, rs[i+1]=inclusive_scan(cnt)[i].
__global__ void k_scan(const int* __restrict__ cnt, int* __restrict__ rs) {
  __shared__ int wsum[4];
  __shared__ int carry;
  int tid = threadIdx.x;
  int wid = tid >> 6, lane = tid & 63;
  if (tid == 0) { carry = 0; rs[0] = 0; }
  __syncthreads();
  for (int base = 0; base < NN; base += 256) {
    int v = (base + tid < NN) ? cnt[base + tid] : 0;
#pragma unroll
    for (int d = 1; d < 64; d <<= 1) {
      int t = __shfl_up(v, d, 64);
      if (lane >= d) v += t;
    }
    if (lane == 63) wsum[wid] = v;
    __syncthreads();
    if (tid == 0) {
      int s = carry;
#pragma unroll
      for (int w2 = 0; w2 < 4; ++w2) { int t = wsum[w2]; wsum[w2] = s; s += t; }
      carry = s;
    }
    __syncthreads();
    v += wsum[wid];
    if (base + tid < NN) rs[base + tid + 1] = v;
    __syncthreads();
  }
}

// rank[e] = sorted position of edge e; srcS[rank[e]] = src[e].
__global__ void k_rank(const int* __restrict__ dstI, const int* __restrict__ srcI,
                       int* __restrict__ cursor, int* __restrict__ rank,
                       int* __restrict__ srcS) {
  int e = blockIdx.x * blockDim.x + threadIdx.x;
  if (e >= NE) return;
  int p = atomicAdd(&cursor[dstI[e]], 1);
  rank[e] = p;
  srcS[p] = srcI[e];
}

// ---------------------------------------------------------------------------
// out0 = relu(n_feat @ lin0_w + lin0_b).  One wave per node, lane = out col.
// ---------------------------------------------------------------------------
__global__ void k_lin0(const float* __restrict__ nf, const float* __restrict__ w,
                       const float* __restrict__ b, float* __restrict__ outp) {
  int gid = blockIdx.x * blockDim.x + threadIdx.x;
  int n = gid >> 6, lane = gid & 63;
  if (n >= NN) return;
  float xv = (lane < D) ? nf[(size_t)n * D + lane] : 0.f;
  if (lane < D) {
    float acc = b[lane];
    for (int i = 0; i < D; ++i)
      acc += __shfl(xv, i, 64) * w[i * D + lane];
    outp[(size_t)n * D + lane] = fmaxf(acc, 0.f);
  }
}

// ---------------------------------------------------------------------------
// h_e = relu(e_feat @ en1_w + en1_b) -> bf16 [E][128], written in dst-sorted
// order (row rank[e]).
// ---------------------------------------------------------------------------
__global__ void k_en1(const float* __restrict__ ef, const float* __restrict__ w,
                      const float* __restrict__ b, const int* __restrict__ rank,
                      u16* __restrict__ h) {
  int gid = blockIdx.x * blockDim.x + threadIdx.x;
  int e = gid >> 7, k = gid & 127;
  if (e >= NE) return;
  float acc = b[k];
#pragma unroll
  for (int i = 0; i < 10; ++i)
    acc += ef[(size_t)e * 10 + i] * w[i * EH + k];
  h[(size_t)rank[e] * EH + k] = f2bf(fmaxf(acc, 0.f));
}

// ---------------------------------------------------------------------------
// Pack w2 into MFMA A-fragment order (bf16).
// A-frag for i-slice, kstep s, o-frag f: lane l holds 8 elems:
//   row o = f*16 + (l&15), k = s*32 + (l>>4)*8 + j,  value = w2[k, i, o]
// Element offset = (((i*4 + s)*3 + f)*64 + l)*8 + j.
// ---------------------------------------------------------------------------
__global__ void k_packA(const float* __restrict__ w2, u16* __restrict__ Ap) {
  int idx = blockIdx.x * 256 + threadIdx.x;
  if (idx >= D * 4 * 3 * 64 * 8) return;
  int j = idx & 7;
  int t = idx >> 3;
  int l = t & 63; t >>= 6;
  int f = t % 3;  t /= 3;
  int s = t & 3;
  int i = t >> 2;
  int k = s * 32 + ((l >> 4) << 3) + j;
  int o = f * 16 + (l & 15);
  float v = (o < D) ? w2[(size_t)k * DD + i * D + o] : 0.f;
  Ap[idx] = f2bf(v);
}

// b2 (en2_b reshaped [42][42]) packed as A-frags: row o, k = i-index.
__global__ void k_packB2(const float* __restrict__ e2b, u16* __restrict__ b2p) {
  int idx = blockIdx.x * 256 + threadIdx.x;
  if (idx >= 2 * 3 * 64 * 8) return;
  int j = idx & 7;
  int t = idx >> 3;
  int l = t & 63; t >>= 6;
  int f = t % 3;
  int s = t / 3;
  int k = s * 32 + ((l >> 4) << 3) + j;
  int o = f * 16 + (l & 15);
  float v = (k < D && o < D) ? e2b[k * D + o] : 0.f;
  b2p[idx] = f2bf(v);
}

// ---------------------------------------------------------------------------
// Fused NNConv message kernel, MFMA path. Edges are dst-sorted; messages are
// written LINEARLY to msg[E][MS] (no atomics). Aggregation happens in
// k_node_update via CSR row ranges.
// ---------------------------------------------------------------------------
__launch_bounds__(256, 4)
__global__ void k_edge_mfma(const float* __restrict__ outp, const u16* __restrict__ hbf,
                            const u16* __restrict__ Ap, const u16* __restrict__ b2p,
                            const int* __restrict__ srcS, float* __restrict__ msg) {
  // LDS: xT [42][64] f32 (10752 B) | region2: {hls 16KB + xbf 8KB} later {red [2][64][52] f32 = 26624 B}
  __shared__ __align__(16) char smem[10752 + 26624];
  float* xT = (float*)smem;
  char*  hls = smem + 10752;
  char*  xbf = smem + 10752 + 16384;
  float* red = (float*)(smem + 10752);

  int tid = threadIdx.x;
  long et = (long)blockIdx.x * 64;
  int ne = (int)(NE - et); if (ne > 64) ne = 64;

  // ---- stage h tile [64][128] bf16, XOR-swizzled rows ----
  for (int c = tid; c < 1024; c += 256) {
    int row = c >> 4;
    int off = (c & 15) << 4;  // byte offset within 256B row
    uint4 v = {0, 0, 0, 0};
    if (row < ne) v = *(const uint4*)(hbf + (et + row) * EH + (off >> 1));
    *(uint4*)(hls + row * 256 + (off ^ ((row & 7) << 4))) = v;
  }
  // ---- stage x = out[srcS[p]]: xT transposed f32 + xbf row-major bf16 (swizzled) ----
  {
    int r = tid >> 2, j = tid & 3;
    const float* xr = (r < ne) ? (outp + (size_t)srcS[et + r] * D) : nullptr;
    for (int i = j; i < D; i += 4) {
      float v = xr ? xr[i] : 0.f;
      xT[i * 64 + r] = v;
      int bo = (r * 128 + i * 2) ^ ((r & 7) << 4);
      *(u16*)(xbf + bo) = f2bf(v);
    }
    for (int i = D + j; i < 64; i += 4) {
      int bo = (r * 128 + i * 2) ^ ((r & 7) << 4);
      *(u16*)(xbf + bo) = 0;
    }
  }
  __syncthreads();

  int w = tid >> 6;   // wave id = k-step
  int l = tid & 63;
  int e16 = l & 15;
  int kg = l >> 4;

  // ---- hoist h B-frags (one k-step, 4 edge-groups) into registers ----
  bf8 hf[4];
  {
    int kb = (w * 32 + kg * 8) * 2;
    int sw = (e16 & 7) << 4;
#pragma unroll
    for (int g = 0; g < 4; ++g)
      hf[g] = *(const bf8*)(hls + (g * 16 + e16) * 256 + (kb ^ sw));
  }

  f4 macc[4][3];
#pragma unroll
  for (int g = 0; g < 4; ++g)
#pragma unroll
    for (int f = 0; f < 3; ++f)
      macc[g][f] = (f4){0.f, 0.f, 0.f, 0.f};

  const u16* apw = Ap + (size_t)w * 1536 + (size_t)l * 8;

#define COMPUTE(ii, AA)                                                         \
  {                                                                             \
    _Pragma("unroll")                                                           \
    for (int g = 0; g < 4; ++g) {                                               \
      float xs = xT[(ii) * 64 + g * 16 + e16];                                  \
      f4 zz = {0.f, 0.f, 0.f, 0.f};                                             \
      f4 q0 = __builtin_amdgcn_mfma_f32_16x16x32_bf16(AA[0], hf[g], zz, 0, 0, 0); \
      f4 q1 = __builtin_amdgcn_mfma_f32_16x16x32_bf16(AA[1], hf[g], zz, 0, 0, 0); \
      f4 q2 = __builtin_amdgcn_mfma_f32_16x16x32_bf16(AA[2], hf[g], zz, 0, 0, 0); \
      macc[g][0] += xs * q0;                                                    \
      macc[g][1] += xs * q1;                                                    \
      macc[g][2] += xs * q2;                                                    \
    }                                                                           \
  }

  // ---- main loop over 42 i-slices, A double-buffered ----
  bf8 A0[3], A1[3];
#pragma unroll
  for (int f = 0; f < 3; ++f) A0[f] = *(const bf8*)(apw + f * 512);
#pragma unroll 1
  for (int i = 0; i < D; i += 2) {
    const u16* pn = apw + (size_t)(i + 1) * 6144;
#pragma unroll
    for (int f = 0; f < 3; ++f) A1[f] = *(const bf8*)(pn + f * 512);
    COMPUTE(i, A0);
    if (i + 2 < D) {
      const u16* pn2 = apw + (size_t)(i + 2) * 6144;
#pragma unroll
      for (int f = 0; f < 3; ++f) A0[f] = *(const bf8*)(pn2 + f * 512);
    }
    COMPUTE(i + 1, A1);
  }

  // ---- b2 epilogue: waves 0,1 add (x @ b2)^T via 2 k-steps over i ----
  if (w < 2) {
    const u16* bpw = b2p + (size_t)w * 1536 + (size_t)l * 8;
    bf8 B0 = *(const bf8*)(bpw);
    bf8 B1 = *(const bf8*)(bpw + 512);
    bf8 B2 = *(const bf8*)(bpw + 1024);
    int kb = (w * 32 + kg * 8) * 2;
    int sw = (e16 & 7) << 4;
#pragma unroll
    for (int g = 0; g < 4; ++g) {
      bf8 bx = *(const bf8*)(xbf + (g * 16 + e16) * 128 + (kb ^ sw));
      macc[g][0] = __builtin_amdgcn_mfma_f32_16x16x32_bf16(B0, bx, macc[g][0], 0, 0, 0);
      macc[g][1] = __builtin_amdgcn_mfma_f32_16x16x32_bf16(B1, bx, macc[g][1], 0, 0, 0);
      macc[g][2] = __builtin_amdgcn_mfma_f32_16x16x32_bf16(B2, bx, macc[g][2], 0, 0, 0);
    }
  }

  // ---- cross-wave reduction through LDS (red overlays hls/xbf) ----
  __syncthreads();
  if (w < 2) {
#pragma unroll
    for (int g = 0; g < 4; ++g)
#pragma unroll
      for (int f = 0; f < 3; ++f)
        *(f4*)&red[((size_t)w * 64 + g * 16 + e16) * 52 + f * 16 + kg * 4] = macc[g][f];
  }
  __syncthreads();
  if (w >= 2) {
#pragma unroll
    for (int g = 0; g < 4; ++g)
#pragma unroll
      for (int f = 0; f < 3; ++f) {
        float* rp = &red[((size_t)(w - 2) * 64 + g * 16 + e16) * 52 + f * 16 + kg * 4];
        f4 v = *(f4*)rp;
        v += macc[g][f];
        *(f4*)rp = v;
      }
  }
  __syncthreads();
  {
    int e = tid >> 2, c = tid & 3;
    if (e < ne) {
      float* mrow = msg + (size_t)(et + e) * MS;
#pragma unroll
      for (int u = 0; u < 3; ++u) {
        int o0 = c * 12 + u * 4;
        f4 v0 = *(f4*)&red[(size_t)e * 52 + o0];
        f4 v1 = *(f4*)&red[((size_t)(64 + e)) * 52 + o0];
        f4 s = v0 + v1;
        *(f4*)(mrow + o0) = s;   // cols >= 42 are pad; node kernel ignores
      }
    }
  }
#undef COMPUTE
}

// ---------------------------------------------------------------------------
// Node update with fused CSR aggregation:
// aggr = sum over msg rows [rs[n], rs[n+1]); m = relu(aggr + out + conv_bias);
// out_new = concat([m, out]) @ msg_w + msg_b;  last step: d_out = out_new + n_feat
// ---------------------------------------------------------------------------
__global__ void k_node_update(const float* __restrict__ msg, const int* __restrict__ rs,
                              const float* __restrict__ outp,
                              const float* __restrict__ cb, const float* __restrict__ mw,
                              const float* __restrict__ mb, float* __restrict__ newout,
                              const float* __restrict__ nf, void* __restrict__ fout,
                              int last, const int* __restrict__ flag) {
  int gid = blockIdx.x * blockDim.x + threadIdx.x;
  int n = gid >> 6, lane = gid & 63;
  if (n >= NN) return;
  float ov = (lane < D) ? outp[(size_t)n * D + lane] : 0.f;
  float av = 0.f;
  int r0 = rs[n], r1 = rs[n + 1];
  if (lane < D)
    for (int r = r0; r < r1; ++r)
      av += msg[(size_t)r * MS + lane];
  float mv = 0.f;
  if (lane < D) mv = fmaxf(av + ov + cb[lane], 0.f);
  if (lane < D) {
    float acc = mb[lane];
    for (int i = 0; i < D; ++i)
      acc += __shfl(mv, i, 64) * mw[i * D + lane];
    for (int i = 0; i < D; ++i)
      acc += __shfl(ov, i, 64) * mw[(D + i) * D + lane];
    size_t idx = (size_t)n * D + lane;
    if (last) {
      float res = acc + nf[idx];
      if (flag[0]) ((u16*)fout)[idx] = f2bf(res);
      else         ((float*)fout)[idx] = res;
    } else {
      newout[idx] = acc;
    }
  }
}

// ---------------------------------------------------------------------------
extern "C" void kernel_launch(void* const* d_in, const int* in_sizes, int n_in,
                              void* d_out, int out_size, void* d_ws, size_t ws_size,
                              hipStream_t stream) {
  (void)in_sizes; (void)n_in; (void)out_size; (void)ws_size;
  const void* nf   = d_in[0];
  const void* ef   = d_in[1];
  const int*  srcI = (const int*)d_in[2];
  const int*  dstI = (const int*)d_in[3];
  const void* l0w = d_in[4];  const void* l0b = d_in[5];
  const void* e1w = d_in[6];  const void* e1b = d_in[7];
  const void* e2w = d_in[8];  const void* e2b = d_in[9];
  const void* cbI = d_in[10]; const void* mwI = d_in[11]; const void* mbI = d_in[12];

  char* ws = (char*)d_ws;
  size_t off = 0;
  auto alloc = [&](size_t bytes) -> void* {
    void* p = ws + off;
    off = (off + bytes + 255) & ~(size_t)255;
    return p;
  };

  int*   flag  = (int*)alloc(4);
  float* c_nf  = (float*)alloc((size_t)NN * D * 4);
  float* c_ef  = (float*)alloc((size_t)NE * 10 * 4);
  float* c_l0w = (float*)alloc(D * D * 4);
  float* c_l0b = (float*)alloc(D * 4);
  float* c_e1w = (float*)alloc(10 * EH * 4);
  float* c_e1b = (float*)alloc(EH * 4);
  float* c_e2w = (float*)alloc((size_t)EH * DD * 4);
  float* c_e2b = (float*)alloc(DD * 4);
  float* c_cb  = (float*)alloc(D * 4);
  float* c_mw  = (float*)alloc(2 * D * D * 4);
  float* c_mb  = (float*)alloc(D * 4);
  float* out_a = (float*)alloc((size_t)NN * D * 4);
  float* out_b = (float*)alloc((size_t)NN * D * 4);
  u16*   hbf   = (u16*)alloc((size_t)NE * EH * 2);
  u16*   Ap    = (u16*)alloc((size_t)D * 4 * 3 * 64 * 8 * 2);
  u16*   b2p   = (u16*)alloc((size_t)2 * 3 * 64 * 8 * 2);
  int*   cnt    = (int*)alloc((size_t)NN * 4);
  int*   rowst  = (int*)alloc((size_t)(NN + 1) * 4);
  int*   cursor = (int*)alloc((size_t)NN * 4);
  int*   rank   = (int*)alloc((size_t)NE * 4);
  int*   srcS   = (int*)alloc((size_t)NE * 4);
  float* msg    = (float*)alloc((size_t)NE * MS * 4);

  // dtype probe + canonicalization to fp32
  k_detect<<<1, 256, 0, stream>>>((const u32*)nf, flag);
  auto cvt = [&](const void* s, float* dPtr, int count) {
    k_cvt<<<(count + 255) / 256, 256, 0, stream>>>(s, dPtr, count, flag);
  };
  cvt(nf,  c_nf,  NN * D);
  cvt(ef,  c_ef,  NE * 10);
  cvt(l0w, c_l0w, D * D);
  cvt(l0b, c_l0b, D);
  cvt(e1w, c_e1w, 10 * EH);
  cvt(e1b, c_e1b, EH);
  cvt(e2w, c_e2w, EH * DD);
  cvt(e2b, c_e2b, DD);
  cvt(cbI, c_cb,  D);
  cvt(mwI, c_mw,  2 * D * D);
  cvt(mbI, c_mb,  D);

  // CSR build (dst constant across steps — once per launch)
  (void)hipMemsetAsync(cnt, 0, (size_t)NN * 4, stream);
  k_hist<<<(NE + 255) / 256, 256, 0, stream>>>(dstI, cnt);
  k_scan<<<1, 256, 0, stream>>>(cnt, rowst);
  (void)hipMemcpyAsync(cursor, rowst, (size_t)NN * 4, hipMemcpyDeviceToDevice, stream);
  k_rank<<<(NE + 255) / 256, 256, 0, stream>>>(dstI, srcI, cursor, rank, srcS);

  // node init + edge network (dst-sorted) + fragment packing
  k_lin0<<<(NN * 64 + 255) / 256, 256, 0, stream>>>(c_nf, c_l0w, c_l0b, out_a);
  k_en1<<<(NE * 128 + 255) / 256, 256, 0, stream>>>(c_ef, c_e1w, c_e1b, rank, hbf);
  k_packA<<<(D * 4 * 3 * 64 * 8 + 255) / 256, 256, 0, stream>>>(c_e2w, Ap);
  k_packB2<<<(2 * 3 * 64 * 8 + 255) / 256, 256, 0, stream>>>(c_e2b, b2p);

  int nblk = (NE + 63) / 64;
  float* cur = out_a;
  float* nxt = out_b;
  for (int s = 0; s < STEPS; ++s) {
    k_edge_mfma<<<nblk, 256, 0, stream>>>(cur, hbf, Ap, b2p, srcS, msg);
    int last = (s == STEPS - 1) ? 1 : 0;
    k_node_update<<<(NN * 64 + 255) / 256, 256, 0, stream>>>(
        msg, rowst, cur, c_cb, c_mw, c_mb, nxt, c_nf, d_out, last, flag);
    float* t = cur; cur = nxt; nxt = t;
  }
}

// Round 2
// 1080.192 us; speedup vs baseline: 2.1214x; 2.0265x over previous
//
#include <hip/hip_runtime.h>

typedef unsigned short u16;
typedef unsigned int u32;

#define NN 50000
#define NE 150000
#define D 42
#define EH 128
#define DD 1764   // D*D
#define STEPS 6
#define MS 48     // msg row stride (floats), 192 B = 16B-aligned

typedef __attribute__((ext_vector_type(8))) short bf8;
typedef __attribute__((ext_vector_type(4))) float f4;

static __device__ __forceinline__ float bf2f(u16 v) {
  return __uint_as_float(((u32)v) << 16);
}
static __device__ __forceinline__ u16 f2bf(float f) {
  u32 x = __float_as_uint(f);
  return (u16)((x + 0x7fffu + ((x >> 16) & 1u)) >> 16);  // RNE
}

// ---------------------------------------------------------------------------
// Dtype probe (bf16 vs fp32 inputs).
// ---------------------------------------------------------------------------
__global__ void k_detect(const u32* __restrict__ words, int* __restrict__ flag) {
  __shared__ int cnt;
  if (threadIdx.x == 0) cnt = 0;
  __syncthreads();
  int bad = 0;
  for (int i = threadIdx.x; i < 4096; i += 256) {
    u32 w = words[i];
    float v = __uint_as_float((w & 0xffffu) << 16);
    float a = fabsf(v);
    if (!(a < 16.0f)) bad++;
  }
  if (bad) atomicAdd(&cnt, bad);
  __syncthreads();
  if (threadIdx.x == 0) flag[0] = (cnt < 100) ? 1 : 0;
}

__global__ void k_cvt(const void* __restrict__ src, float* __restrict__ dst,
                      int count, const int* __restrict__ flag) {
  int i = blockIdx.x * blockDim.x + threadIdx.x;
  if (i >= count) return;
  if (flag[0]) dst[i] = bf2f(((const u16*)src)[i]);
  else         dst[i] = ((const float*)src)[i];
}

// ---------------------------------------------------------------------------
// CSR build: histogram of dst, block-scan to row starts, rank assignment.
// dst is constant across the 6 steps so this is once per launch.
// ---------------------------------------------------------------------------
__global__ void k_hist(const int* __restrict__ dstI, int* __restrict__ cnt) {
  int e = blockIdx.x * blockDim.x + threadIdx.x;
  if (e < NE) atomicAdd(&cnt[dstI[e]], 1);
}

// Single-block running scan: rs[0]=0, rs[i+1]=inclusive_scan(cnt)[i].
__global__ void k_scan(const int* __restrict__ cnt, int* __restrict__ rs) {
  __shared__ int wsum[4];
  __shared__ int carry;
  int tid = threadIdx.x;
  int wid = tid >> 6, lane = tid & 63;
  if (tid == 0) { carry = 0; rs[0] = 0; }
  __syncthreads();
  for (int base = 0; base < NN; base += 256) {
    int v = (base + tid < NN) ? cnt[base + tid] : 0;
#pragma unroll
    for (int d = 1; d < 64; d <<= 1) {
      int t = __shfl_up(v, d, 64);
      if (lane >= d) v += t;
    }
    if (lane == 63) wsum[wid] = v;
    __syncthreads();
    if (tid == 0) {
      int s = carry;
#pragma unroll
      for (int w2 = 0; w2 < 4; ++w2) { int t = wsum[w2]; wsum[w2] = s; s += t; }
      carry = s;
    }
    __syncthreads();
    v += wsum[wid];
    if (base + tid < NN) rs[base + tid + 1] = v;
    __syncthreads();
  }
}

// rank[e] = sorted position of edge e; srcS[rank[e]] = src[e].
__global__ void k_rank(const int* __restrict__ dstI, const int* __restrict__ srcI,
                       int* __restrict__ cursor, int* __restrict__ rank,
                       int* __restrict__ srcS) {
  int e = blockIdx.x * blockDim.x + threadIdx.x;
  if (e >= NE) return;
  int p = atomicAdd(&cursor[dstI[e]], 1);
  rank[e] = p;
  srcS[p] = srcI[e];
}

// ---------------------------------------------------------------------------
// out0 = relu(n_feat @ lin0_w + lin0_b).  One wave per node, lane = out col.
// ---------------------------------------------------------------------------
__global__ void k_lin0(const float* __restrict__ nf, const float* __restrict__ w,
                       const float* __restrict__ b, float* __restrict__ outp) {
  int gid = blockIdx.x * blockDim.x + threadIdx.x;
  int n = gid >> 6, lane = gid & 63;
  if (n >= NN) return;
  float xv = (lane < D) ? nf[(size_t)n * D + lane] : 0.f;
  if (lane < D) {
    float acc = b[lane];
    for (int i = 0; i < D; ++i)
      acc += __shfl(xv, i, 64) * w[i * D + lane];
    outp[(size_t)n * D + lane] = fmaxf(acc, 0.f);
  }
}

// ---------------------------------------------------------------------------
// h_e = relu(e_feat @ en1_w + en1_b) -> bf16 [E][128], written in dst-sorted
// order (row rank[e]).
// ---------------------------------------------------------------------------
__global__ void k_en1(const float* __restrict__ ef, const float* __restrict__ w,
                      const float* __restrict__ b, const int* __restrict__ rank,
                      u16* __restrict__ h) {
  int gid = blockIdx.x * blockDim.x + threadIdx.x;
  int e = gid >> 7, k = gid & 127;
  if (e >= NE) return;
  float acc = b[k];
#pragma unroll
  for (int i = 0; i < 10; ++i)
    acc += ef[(size_t)e * 10 + i] * w[i * EH + k];
  h[(size_t)rank[e] * EH + k] = f2bf(fmaxf(acc, 0.f));
}

// ---------------------------------------------------------------------------
// Pack w2 into MFMA A-fragment order (bf16).
// A-frag for i-slice, kstep s, o-frag f: lane l holds 8 elems:
//   row o = f*16 + (l&15), k = s*32 + (l>>4)*8 + j,  value = w2[k, i, o]
// Element offset = (((i*4 + s)*3 + f)*64 + l)*8 + j.
// ---------------------------------------------------------------------------
__global__ void k_packA(const float* __restrict__ w2, u16* __restrict__ Ap) {
  int idx = blockIdx.x * 256 + threadIdx.x;
  if (idx >= D * 4 * 3 * 64 * 8) return;
  int j = idx & 7;
  int t = idx >> 3;
  int l = t & 63; t >>= 6;
  int f = t % 3;  t /= 3;
  int s = t & 3;
  int i = t >> 2;
  int k = s * 32 + ((l >> 4) << 3) + j;
  int o = f * 16 + (l & 15);
  float v = (o < D) ? w2[(size_t)k * DD + i * D + o] : 0.f;
  Ap[idx] = f2bf(v);
}

// b2 (en2_b reshaped [42][42]) packed as A-frags: row o, k = i-index.
__global__ void k_packB2(const float* __restrict__ e2b, u16* __restrict__ b2p) {
  int idx = blockIdx.x * 256 + threadIdx.x;
  if (idx >= 2 * 3 * 64 * 8) return;
  int j = idx & 7;
  int t = idx >> 3;
  int l = t & 63; t >>= 6;
  int f = t % 3;
  int s = t / 3;
  int k = s * 32 + ((l >> 4) << 3) + j;
  int o = f * 16 + (l & 15);
  float v = (k < D && o < D) ? e2b[k * D + o] : 0.f;
  b2p[idx] = f2bf(v);
}

// ---------------------------------------------------------------------------
// Fused NNConv message kernel, MFMA path. Edges are dst-sorted; messages are
// written LINEARLY to msg[E][MS] (no atomics). Aggregation happens in
// k_node_update via CSR row ranges.
// __launch_bounds__(256,3): (256,4) capped VGPR at 64 -> per-iteration spills
// (WRITE_SIZE 593 MB vs 29 MB ideal). 76 VGPR @ 3 waves/EU is the no-spill point.
// ---------------------------------------------------------------------------
__launch_bounds__(256, 3)
__global__ void k_edge_mfma(const float* __restrict__ outp, const u16* __restrict__ hbf,
                            const u16* __restrict__ Ap, const u16* __restrict__ b2p,
                            const int* __restrict__ srcS, float* __restrict__ msg) {
  // LDS: xT [42][64] f32 (10752 B) | region2: {hls 16KB + xbf 8KB} later {red [2][64][52] f32 = 26624 B}
  __shared__ __align__(16) char smem[10752 + 26624];
  float* xT = (float*)smem;
  char*  hls = smem + 10752;
  char*  xbf = smem + 10752 + 16384;
  float* red = (float*)(smem + 10752);

  int tid = threadIdx.x;
  long et = (long)blockIdx.x * 64;
  int ne = (int)(NE - et); if (ne > 64) ne = 64;

  // ---- stage h tile [64][128] bf16, XOR-swizzled rows ----
  for (int c = tid; c < 1024; c += 256) {
    int row = c >> 4;
    int off = (c & 15) << 4;  // byte offset within 256B row
    uint4 v = {0, 0, 0, 0};
    if (row < ne) v = *(const uint4*)(hbf + (et + row) * EH + (off >> 1));
    *(uint4*)(hls + row * 256 + (off ^ ((row & 7) << 4))) = v;
  }
  // ---- stage x = out[srcS[p]]: xT transposed f32 + xbf row-major bf16 (swizzled) ----
  {
    int r = tid >> 2, j = tid & 3;
    const float* xr = (r < ne) ? (outp + (size_t)srcS[et + r] * D) : nullptr;
    for (int i = j; i < D; i += 4) {
      float v = xr ? xr[i] : 0.f;
      xT[i * 64 + r] = v;
      int bo = (r * 128 + i * 2) ^ ((r & 7) << 4);
      *(u16*)(xbf + bo) = f2bf(v);
    }
    for (int i = D + j; i < 64; i += 4) {
      int bo = (r * 128 + i * 2) ^ ((r & 7) << 4);
      *(u16*)(xbf + bo) = 0;
    }
  }
  __syncthreads();

  int w = tid >> 6;   // wave id = k-step
  int l = tid & 63;
  int e16 = l & 15;
  int kg = l >> 4;

  // ---- hoist h B-frags (one k-step, 4 edge-groups) into registers ----
  bf8 hf[4];
  {
    int kb = (w * 32 + kg * 8) * 2;
    int sw = (e16 & 7) << 4;
#pragma unroll
    for (int g = 0; g < 4; ++g)
      hf[g] = *(const bf8*)(hls + (g * 16 + e16) * 256 + (kb ^ sw));
  }

  f4 macc[4][3];
#pragma unroll
  for (int g = 0; g < 4; ++g)
#pragma unroll
    for (int f = 0; f < 3; ++f)
      macc[g][f] = (f4){0.f, 0.f, 0.f, 0.f};

  const u16* apw = Ap + (size_t)w * 1536 + (size_t)l * 8;

#define COMPUTE(ii, AA)                                                         \
  {                                                                             \
    _Pragma("unroll")                                                           \
    for (int g = 0; g < 4; ++g) {                                               \
      float xs = xT[(ii) * 64 + g * 16 + e16];                                  \
      f4 zz = {0.f, 0.f, 0.f, 0.f};                                             \
      f4 q0 = __builtin_amdgcn_mfma_f32_16x16x32_bf16(AA[0], hf[g], zz, 0, 0, 0); \
      f4 q1 = __builtin_amdgcn_mfma_f32_16x16x32_bf16(AA[1], hf[g], zz, 0, 0, 0); \
      f4 q2 = __builtin_amdgcn_mfma_f32_16x16x32_bf16(AA[2], hf[g], zz, 0, 0, 0); \
      macc[g][0] += xs * q0;                                                    \
      macc[g][1] += xs * q1;                                                    \
      macc[g][2] += xs * q2;                                                    \
    }                                                                           \
  }

  // ---- main loop over 42 i-slices, A double-buffered ----
  bf8 A0[3], A1[3];
#pragma unroll
  for (int f = 0; f < 3; ++f) A0[f] = *(const bf8*)(apw + f * 512);
#pragma unroll 1
  for (int i = 0; i < D; i += 2) {
    const u16* pn = apw + (size_t)(i + 1) * 6144;
#pragma unroll
    for (int f = 0; f < 3; ++f) A1[f] = *(const bf8*)(pn + f * 512);
    COMPUTE(i, A0);
    if (i + 2 < D) {
      const u16* pn2 = apw + (size_t)(i + 2) * 6144;
#pragma unroll
      for (int f = 0; f < 3; ++f) A0[f] = *(const bf8*)(pn2 + f * 512);
    }
    COMPUTE(i + 1, A1);
  }

  // ---- b2 epilogue: waves 0,1 add (x @ b2)^T via 2 k-steps over i ----
  if (w < 2) {
    const u16* bpw = b2p + (size_t)w * 1536 + (size_t)l * 8;
    bf8 B0 = *(const bf8*)(bpw);
    bf8 B1 = *(const bf8*)(bpw + 512);
    bf8 B2 = *(const bf8*)(bpw + 1024);
    int kb = (w * 32 + kg * 8) * 2;
    int sw = (e16 & 7) << 4;
#pragma unroll
    for (int g = 0; g < 4; ++g) {
      bf8 bx = *(const bf8*)(xbf + (g * 16 + e16) * 128 + (kb ^ sw));
      macc[g][0] = __builtin_amdgcn_mfma_f32_16x16x32_bf16(B0, bx, macc[g][0], 0, 0, 0);
      macc[g][1] = __builtin_amdgcn_mfma_f32_16x16x32_bf16(B1, bx, macc[g][1], 0, 0, 0);
      macc[g][2] = __builtin_amdgcn_mfma_f32_16x16x32_bf16(B2, bx, macc[g][2], 0, 0, 0);
    }
  }

  // ---- cross-wave reduction through LDS (red overlays hls/xbf) ----
  __syncthreads();
  if (w < 2) {
#pragma unroll
    for (int g = 0; g < 4; ++g)
#pragma unroll
      for (int f = 0; f < 3; ++f)
        *(f4*)&red[((size_t)w * 64 + g * 16 + e16) * 52 + f * 16 + kg * 4] = macc[g][f];
  }
  __syncthreads();
  if (w >= 2) {
#pragma unroll
    for (int g = 0; g < 4; ++g)
#pragma unroll
      for (int f = 0; f < 3; ++f) {
        float* rp = &red[((size_t)(w - 2) * 64 + g * 16 + e16) * 52 + f * 16 + kg * 4];
        f4 v = *(f4*)rp;
        v += macc[g][f];
        *(f4*)rp = v;
      }
  }
  __syncthreads();
  {
    int e = tid >> 2, c = tid & 3;
    if (e < ne) {
      float* mrow = msg + (size_t)(et + e) * MS;
#pragma unroll
      for (int u = 0; u < 3; ++u) {
        int o0 = c * 12 + u * 4;
        f4 v0 = *(f4*)&red[(size_t)e * 52 + o0];
        f4 v1 = *(f4*)&red[((size_t)(64 + e)) * 52 + o0];
        f4 s = v0 + v1;
        *(f4*)(mrow + o0) = s;   // cols >= 42 are pad; node kernel ignores
      }
    }
  }
#undef COMPUTE
}

// ---------------------------------------------------------------------------
// Node update with fused CSR aggregation:
// aggr = sum over msg rows [rs[n], rs[n+1]); m = relu(aggr + out + conv_bias);
// out_new = concat([m, out]) @ msg_w + msg_b;  last step: d_out = out_new + n_feat
// ---------------------------------------------------------------------------
__global__ void k_node_update(const float* __restrict__ msg, const int* __restrict__ rs,
                              const float* __restrict__ outp,
                              const float* __restrict__ cb, const float* __restrict__ mw,
                              const float* __restrict__ mb, float* __restrict__ newout,
                              const float* __restrict__ nf, void* __restrict__ fout,
                              int last, const int* __restrict__ flag) {
  int gid = blockIdx.x * blockDim.x + threadIdx.x;
  int n = gid >> 6, lane = gid & 63;
  if (n >= NN) return;
  float ov = (lane < D) ? outp[(size_t)n * D + lane] : 0.f;
  float av = 0.f;
  int r0 = rs[n], r1 = rs[n + 1];
  if (lane < D)
    for (int r = r0; r < r1; ++r)
      av += msg[(size_t)r * MS + lane];
  float mv = 0.f;
  if (lane < D) mv = fmaxf(av + ov + cb[lane], 0.f);
  if (lane < D) {
    float acc = mb[lane];
    for (int i = 0; i < D; ++i)
      acc += __shfl(mv, i, 64) * mw[i * D + lane];
    for (int i = 0; i < D; ++i)
      acc += __shfl(ov, i, 64) * mw[(D + i) * D + lane];
    size_t idx = (size_t)n * D + lane;
    if (last) {
      float res = acc + nf[idx];
      if (flag[0]) ((u16*)fout)[idx] = f2bf(res);
      else         ((float*)fout)[idx] = res;
    } else {
      newout[idx] = acc;
    }
  }
}

// ---------------------------------------------------------------------------
extern "C" void kernel_launch(void* const* d_in, const int* in_sizes, int n_in,
                              void* d_out, int out_size, void* d_ws, size_t ws_size,
                              hipStream_t stream) {
  (void)in_sizes; (void)n_in; (void)out_size; (void)ws_size;
  const void* nf   = d_in[0];
  const void* ef   = d_in[1];
  const int*  srcI = (const int*)d_in[2];
  const int*  dstI = (const int*)d_in[3];
  const void* l0w = d_in[4];  const void* l0b = d_in[5];
  const void* e1w = d_in[6];  const void* e1b = d_in[7];
  const void* e2w = d_in[8];  const void* e2b = d_in[9];
  const void* cbI = d_in[10]; const void* mwI = d_in[11]; const void* mbI = d_in[12];

  char* ws = (char*)d_ws;
  size_t off = 0;
  auto alloc = [&](size_t bytes) -> void* {
    void* p = ws + off;
    off = (off + bytes + 255) & ~(size_t)255;
    return p;
  };

  int*   flag  = (int*)alloc(4);
  float* c_nf  = (float*)alloc((size_t)NN * D * 4);
  float* c_ef  = (float*)alloc((size_t)NE * 10 * 4);
  float* c_l0w = (float*)alloc(D * D * 4);
  float* c_l0b = (float*)alloc(D * 4);
  float* c_e1w = (float*)alloc(10 * EH * 4);
  float* c_e1b = (float*)alloc(EH * 4);
  float* c_e2w = (float*)alloc((size_t)EH * DD * 4);
  float* c_e2b = (float*)alloc(DD * 4);
  float* c_cb  = (float*)alloc(D * 4);
  float* c_mw  = (float*)alloc(2 * D * D * 4);
  float* c_mb  = (float*)alloc(D * 4);
  float* out_a = (float*)alloc((size_t)NN * D * 4);
  float* out_b = (float*)alloc((size_t)NN * D * 4);
  u16*   hbf   = (u16*)alloc((size_t)NE * EH * 2);
  u16*   Ap    = (u16*)alloc((size_t)D * 4 * 3 * 64 * 8 * 2);
  u16*   b2p   = (u16*)alloc((size_t)2 * 3 * 64 * 8 * 2);
  int*   cnt    = (int*)alloc((size_t)NN * 4);
  int*   rowst  = (int*)alloc((size_t)(NN + 1) * 4);
  int*   cursor = (int*)alloc((size_t)NN * 4);
  int*   rank   = (int*)alloc((size_t)NE * 4);
  int*   srcS   = (int*)alloc((size_t)NE * 4);
  float* msg    = (float*)alloc((size_t)NE * MS * 4);

  // dtype probe + canonicalization to fp32
  k_detect<<<1, 256, 0, stream>>>((const u32*)nf, flag);
  auto cvt = [&](const void* s, float* dPtr, int count) {
    k_cvt<<<(count + 255) / 256, 256, 0, stream>>>(s, dPtr, count, flag);
  };
  cvt(nf,  c_nf,  NN * D);
  cvt(ef,  c_ef,  NE * 10);
  cvt(l0w, c_l0w, D * D);
  cvt(l0b, c_l0b, D);
  cvt(e1w, c_e1w, 10 * EH);
  cvt(e1b, c_e1b, EH);
  cvt(e2w, c_e2w, EH * DD);
  cvt(e2b, c_e2b, DD);
  cvt(cbI, c_cb,  D);
  cvt(mwI, c_mw,  2 * D * D);
  cvt(mbI, c_mb,  D);

  // CSR build (dst constant across steps — once per launch)
  (void)hipMemsetAsync(cnt, 0, (size_t)NN * 4, stream);
  k_hist<<<(NE + 255) / 256, 256, 0, stream>>>(dstI, cnt);
  k_scan<<<1, 256, 0, stream>>>(cnt, rowst);
  (void)hipMemcpyAsync(cursor, rowst, (size_t)NN * 4, hipMemcpyDeviceToDevice, stream);
  k_rank<<<(NE + 255) / 256, 256, 0, stream>>>(dstI, srcI, cursor, rank, srcS);

  // node init + edge network (dst-sorted) + fragment packing
  k_lin0<<<(NN * 64 + 255) / 256, 256, 0, stream>>>(c_nf, c_l0w, c_l0b, out_a);
  k_en1<<<(NE * 128 + 255) / 256, 256, 0, stream>>>(c_ef, c_e1w, c_e1b, rank, hbf);
  k_packA<<<(D * 4 * 3 * 64 * 8 + 255) / 256, 256, 0, stream>>>(c_e2w, Ap);
  k_packB2<<<(2 * 3 * 64 * 8 + 255) / 256, 256, 0, stream>>>(c_e2b, b2p);

  int nblk = (NE + 63) / 64;
  float* cur = out_a;
  float* nxt = out_b;
  for (int s = 0; s < STEPS; ++s) {
    k_edge_mfma<<<nblk, 256, 0, stream>>>(cur, hbf, Ap, b2p, srcS, msg);
    int last = (s == STEPS - 1) ? 1 : 0;
    k_node_update<<<(NN * 64 + 255) / 256, 256, 0, stream>>>(
        msg, rowst, cur, c_cb, c_mw, c_mb, nxt, c_nf, d_out, last, flag);
    float* t = cur; cur = nxt; nxt = t;
  }
}

// Round 3
// 957.856 us; speedup vs baseline: 2.3924x; 1.1277x over previous
//
#include <hip/hip_runtime.h>

typedef unsigned short u16;
typedef unsigned int u32;

#define NN 50000
#define NE 150000
#define D 42
#define EH 128
#define DD 1764   // D*D
#define STEPS 6
#define MS 48     // msg row stride (floats), 192 B = 16B-aligned
#define SCAN_NB 196  // (NN + 255) / 256

typedef __attribute__((ext_vector_type(8))) short bf8;
typedef __attribute__((ext_vector_type(4))) float f4;

static __device__ __forceinline__ float bf2f(u16 v) {
  return __uint_as_float(((u32)v) << 16);
}
static __device__ __forceinline__ u16 f2bf(float f) {
  u32 x = __float_as_uint(f);
  return (u16)((x + 0x7fffu + ((x >> 16) & 1u)) >> 16);  // RNE
}

// ---------------------------------------------------------------------------
// Dtype probe (bf16 vs fp32 inputs).
// ---------------------------------------------------------------------------
__global__ void k_detect(const u32* __restrict__ words, int* __restrict__ flag) {
  __shared__ int cnt;
  if (threadIdx.x == 0) cnt = 0;
  __syncthreads();
  int bad = 0;
  for (int i = threadIdx.x; i < 4096; i += 256) {
    u32 w = words[i];
    float v = __uint_as_float((w & 0xffffu) << 16);
    float a = fabsf(v);
    if (!(a < 16.0f)) bad++;
  }
  if (bad) atomicAdd(&cnt, bad);
  __syncthreads();
  if (threadIdx.x == 0) flag[0] = (cnt < 100) ? 1 : 0;
}

__global__ void k_cvt(const void* __restrict__ src, float* __restrict__ dst,
                      int count, const int* __restrict__ flag) {
  int i = blockIdx.x * blockDim.x + threadIdx.x;
  if (i >= count) return;
  if (flag[0]) dst[i] = bf2f(((const u16*)src)[i]);
  else         dst[i] = ((const float*)src)[i];
}

// ---------------------------------------------------------------------------
// CSR build: histogram of dst, hierarchical scan to row starts, rank assign.
// dst is constant across the 6 steps so this is once per launch.
// (Old single-block k_scan was 127 us on one CU; 3-phase version ~12 us.)
// ---------------------------------------------------------------------------
__global__ void k_hist(const int* __restrict__ dstI, int* __restrict__ cnt) {
  int e = blockIdx.x * blockDim.x + threadIdx.x;
  if (e < NE) atomicAdd(&cnt[dstI[e]], 1);
}

// Phase A: per-block (256-wide) inclusive scan; block sums -> part[].
__global__ void k_scanA(const int* __restrict__ cnt, int* __restrict__ loc,
                        int* __restrict__ part) {
  __shared__ int wsum[4];
  int tid = threadIdx.x, wid = tid >> 6, lane = tid & 63;
  int i = blockIdx.x * 256 + tid;
  int v = (i < NN) ? cnt[i] : 0;
#pragma unroll
  for (int d = 1; d < 64; d <<= 1) {
    int t = __shfl_up(v, d, 64);
    if (lane >= d) v += t;
  }
  if (lane == 63) wsum[wid] = v;
  __syncthreads();
  if (tid == 0) {
    int s = 0;
#pragma unroll
    for (int w2 = 0; w2 < 4; ++w2) { int t = wsum[w2]; wsum[w2] = s; s += t; }
    part[blockIdx.x] = s;
  }
  __syncthreads();
  v += wsum[wid];
  if (i < NN) loc[i] = v;
}

// Phase B: single-block exclusive scan of part[SCAN_NB] in place.
__global__ void k_scanB(int* __restrict__ part) {
  __shared__ int wsum[4];
  int tid = threadIdx.x, wid = tid >> 6, lane = tid & 63;
  int v = (tid < SCAN_NB) ? part[tid] : 0;
  int orig = v;
#pragma unroll
  for (int d = 1; d < 64; d <<= 1) {
    int t = __shfl_up(v, d, 64);
    if (lane >= d) v += t;
  }
  if (lane == 63) wsum[wid] = v;
  __syncthreads();
  if (tid == 0) {
    int s = 0;
#pragma unroll
    for (int w2 = 0; w2 < 4; ++w2) { int t = wsum[w2]; wsum[w2] = s; s += t; }
  }
  __syncthreads();
  v += wsum[wid];
  if (tid < SCAN_NB) part[tid] = v - orig;  // exclusive
}

// Phase C: rs[0] = 0; rs[i+1] = loc[i] + part[i>>8].
__global__ void k_scanC(const int* __restrict__ loc, const int* __restrict__ part,
                        int* __restrict__ rs) {
  int i = blockIdx.x * 256 + threadIdx.x;
  if (i == 0) rs[0] = 0;
  if (i < NN) rs[i + 1] = loc[i] + part[blockIdx.x];
}

// rank[e] = sorted position of edge e; srcS[rank[e]] = src[e].
__global__ void k_rank(const int* __restrict__ dstI, const int* __restrict__ srcI,
                       int* __restrict__ cursor, int* __restrict__ rank,
                       int* __restrict__ srcS) {
  int e = blockIdx.x * blockDim.x + threadIdx.x;
  if (e >= NE) return;
  int p = atomicAdd(&cursor[dstI[e]], 1);
  rank[e] = p;
  srcS[p] = srcI[e];
}

// ---------------------------------------------------------------------------
// out0 = relu(n_feat @ lin0_w + lin0_b).  One wave per node, lane = out col.
// ---------------------------------------------------------------------------
__global__ void k_lin0(const float* __restrict__ nf, const float* __restrict__ w,
                       const float* __restrict__ b, float* __restrict__ outp) {
  int gid = blockIdx.x * blockDim.x + threadIdx.x;
  int n = gid >> 6, lane = gid & 63;
  if (n >= NN) return;
  float xv = (lane < D) ? nf[(size_t)n * D + lane] : 0.f;
  if (lane < D) {
    float acc = b[lane];
    for (int i = 0; i < D; ++i)
      acc += __shfl(xv, i, 64) * w[i * D + lane];
    outp[(size_t)n * D + lane] = fmaxf(acc, 0.f);
  }
}

// ---------------------------------------------------------------------------
// h_e = relu(e_feat @ en1_w + en1_b) -> bf16 [E][128], written in dst-sorted
// order (row rank[e]).
// ---------------------------------------------------------------------------
__global__ void k_en1(const float* __restrict__ ef, const float* __restrict__ w,
                      const float* __restrict__ b, const int* __restrict__ rank,
                      u16* __restrict__ h) {
  int gid = blockIdx.x * blockDim.x + threadIdx.x;
  int e = gid >> 7, k = gid & 127;
  if (e >= NE) return;
  float acc = b[k];
#pragma unroll
  for (int i = 0; i < 10; ++i)
    acc += ef[(size_t)e * 10 + i] * w[i * EH + k];
  h[(size_t)rank[e] * EH + k] = f2bf(fmaxf(acc, 0.f));
}

// ---------------------------------------------------------------------------
// Pack w2 into MFMA A-fragment order (bf16).
// A-frag for i-slice, kstep s, o-frag f: lane l holds 8 elems:
//   row o = f*16 + (l&15), k = s*32 + (l>>4)*8 + j,  value = w2[k, i, o]
// Element offset = (((i*4 + s)*3 + f)*64 + l)*8 + j.
// ---------------------------------------------------------------------------
__global__ void k_packA(const float* __restrict__ w2, u16* __restrict__ Ap) {
  int idx = blockIdx.x * 256 + threadIdx.x;
  if (idx >= D * 4 * 3 * 64 * 8) return;
  int j = idx & 7;
  int t = idx >> 3;
  int l = t & 63; t >>= 6;
  int f = t % 3;  t /= 3;
  int s = t & 3;
  int i = t >> 2;
  int k = s * 32 + ((l >> 4) << 3) + j;
  int o = f * 16 + (l & 15);
  float v = (o < D) ? w2[(size_t)k * DD + i * D + o] : 0.f;
  Ap[idx] = f2bf(v);
}

// b2 (en2_b reshaped [42][42]) packed as A-frags: row o, k = i-index.
__global__ void k_packB2(const float* __restrict__ e2b, u16* __restrict__ b2p) {
  int idx = blockIdx.x * 256 + threadIdx.x;
  if (idx >= 2 * 3 * 64 * 8) return;
  int j = idx & 7;
  int t = idx >> 3;
  int l = t & 63; t >>= 6;
  int f = t % 3;
  int s = t / 3;
  int k = s * 32 + ((l >> 4) << 3) + j;
  int o = f * 16 + (l & 15);
  float v = (k < D && o < D) ? e2b[k * D + o] : 0.f;
  b2p[idx] = f2bf(v);
}

// ---------------------------------------------------------------------------
// Fused NNConv message kernel, MFMA path. Edges are dst-sorted; messages are
// written LINEARLY to msg[E][MS] (no atomics). Aggregation happens in
// k_node_update via CSR row ranges.
// __launch_bounds__(256,3): (256,4) capped VGPR at 64 -> per-iteration spills
// (WRITE_SIZE 593 MB vs 29 MB ideal). 76 VGPR @ 3 waves/EU is the no-spill point.
// ---------------------------------------------------------------------------
__launch_bounds__(256, 3)
__global__ void k_edge_mfma(const float* __restrict__ outp, const u16* __restrict__ hbf,
                            const u16* __restrict__ Ap, const u16* __restrict__ b2p,
                            const int* __restrict__ srcS, float* __restrict__ msg) {
  // LDS: xT [42][64] f32 (10752 B) | region2: {hls 16KB + xbf 8KB} later {red [2][64][52] f32 = 26624 B}
  __shared__ __align__(16) char smem[10752 + 26624];
  float* xT = (float*)smem;
  char*  hls = smem + 10752;
  char*  xbf = smem + 10752 + 16384;
  float* red = (float*)(smem + 10752);

  int tid = threadIdx.x;
  long et = (long)blockIdx.x * 64;
  int ne = (int)(NE - et); if (ne > 64) ne = 64;

  // ---- stage h tile [64][128] bf16, XOR-swizzled rows ----
  for (int c = tid; c < 1024; c += 256) {
    int row = c >> 4;
    int off = (c & 15) << 4;  // byte offset within 256B row
    uint4 v = {0, 0, 0, 0};
    if (row < ne) v = *(const uint4*)(hbf + (et + row) * EH + (off >> 1));
    *(uint4*)(hls + row * 256 + (off ^ ((row & 7) << 4))) = v;
  }
  // ---- stage x = out[srcS[p]]: xT transposed f32 + xbf row-major bf16 (swizzled) ----
  {
    int r = tid >> 2, j = tid & 3;
    const float* xr = (r < ne) ? (outp + (size_t)srcS[et + r] * D) : nullptr;
    for (int i = j; i < D; i += 4) {
      float v = xr ? xr[i] : 0.f;
      xT[i * 64 + r] = v;
      int bo = (r * 128 + i * 2) ^ ((r & 7) << 4);
      *(u16*)(xbf + bo) = f2bf(v);
    }
    for (int i = D + j; i < 64; i += 4) {
      int bo = (r * 128 + i * 2) ^ ((r & 7) << 4);
      *(u16*)(xbf + bo) = 0;
    }
  }
  __syncthreads();

  int w = tid >> 6;   // wave id = k-step
  int l = tid & 63;
  int e16 = l & 15;
  int kg = l >> 4;

  // ---- hoist h B-frags (one k-step, 4 edge-groups) into registers ----
  bf8 hf[4];
  {
    int kb = (w * 32 + kg * 8) * 2;
    int sw = (e16 & 7) << 4;
#pragma unroll
    for (int g = 0; g < 4; ++g)
      hf[g] = *(const bf8*)(hls + (g * 16 + e16) * 256 + (kb ^ sw));
  }

  f4 macc[4][3];
#pragma unroll
  for (int g = 0; g < 4; ++g)
#pragma unroll
    for (int f = 0; f < 3; ++f)
      macc[g][f] = (f4){0.f, 0.f, 0.f, 0.f};

  const u16* apw = Ap + (size_t)w * 1536 + (size_t)l * 8;

#define COMPUTE(ii, AA)                                                         \
  {                                                                             \
    _Pragma("unroll")                                                           \
    for (int g = 0; g < 4; ++g) {                                               \
      float xs = xT[(ii) * 64 + g * 16 + e16];                                  \
      f4 zz = {0.f, 0.f, 0.f, 0.f};                                             \
      f4 q0 = __builtin_amdgcn_mfma_f32_16x16x32_bf16(AA[0], hf[g], zz, 0, 0, 0); \
      f4 q1 = __builtin_amdgcn_mfma_f32_16x16x32_bf16(AA[1], hf[g], zz, 0, 0, 0); \
      f4 q2 = __builtin_amdgcn_mfma_f32_16x16x32_bf16(AA[2], hf[g], zz, 0, 0, 0); \
      macc[g][0] += xs * q0;                                                    \
      macc[g][1] += xs * q1;                                                    \
      macc[g][2] += xs * q2;                                                    \
    }                                                                           \
  }

  // ---- main loop over 42 i-slices, A double-buffered ----
  bf8 A0[3], A1[3];
#pragma unroll
  for (int f = 0; f < 3; ++f) A0[f] = *(const bf8*)(apw + f * 512);
#pragma unroll 1
  for (int i = 0; i < D; i += 2) {
    const u16* pn = apw + (size_t)(i + 1) * 6144;
#pragma unroll
    for (int f = 0; f < 3; ++f) A1[f] = *(const bf8*)(pn + f * 512);
    COMPUTE(i, A0);
    if (i + 2 < D) {
      const u16* pn2 = apw + (size_t)(i + 2) * 6144;
#pragma unroll
      for (int f = 0; f < 3; ++f) A0[f] = *(const bf8*)(pn2 + f * 512);
    }
    COMPUTE(i + 1, A1);
  }

  // ---- b2 epilogue: waves 0,1 add (x @ b2)^T via 2 k-steps over i ----
  if (w < 2) {
    const u16* bpw = b2p + (size_t)w * 1536 + (size_t)l * 8;
    bf8 B0 = *(const bf8*)(bpw);
    bf8 B1 = *(const bf8*)(bpw + 512);
    bf8 B2 = *(const bf8*)(bpw + 1024);
    int kb = (w * 32 + kg * 8) * 2;
    int sw = (e16 & 7) << 4;
#pragma unroll
    for (int g = 0; g < 4; ++g) {
      bf8 bx = *(const bf8*)(xbf + (g * 16 + e16) * 128 + (kb ^ sw));
      macc[g][0] = __builtin_amdgcn_mfma_f32_16x16x32_bf16(B0, bx, macc[g][0], 0, 0, 0);
      macc[g][1] = __builtin_amdgcn_mfma_f32_16x16x32_bf16(B1, bx, macc[g][1], 0, 0, 0);
      macc[g][2] = __builtin_amdgcn_mfma_f32_16x16x32_bf16(B2, bx, macc[g][2], 0, 0, 0);
    }
  }

  // ---- cross-wave reduction through LDS (red overlays hls/xbf) ----
  __syncthreads();
  if (w < 2) {
#pragma unroll
    for (int g = 0; g < 4; ++g)
#pragma unroll
      for (int f = 0; f < 3; ++f)
        *(f4*)&red[((size_t)w * 64 + g * 16 + e16) * 52 + f * 16 + kg * 4] = macc[g][f];
  }
  __syncthreads();
  if (w >= 2) {
#pragma unroll
    for (int g = 0; g < 4; ++g)
#pragma unroll
      for (int f = 0; f < 3; ++f) {
        float* rp = &red[((size_t)(w - 2) * 64 + g * 16 + e16) * 52 + f * 16 + kg * 4];
        f4 v = *(f4*)rp;
        v += macc[g][f];
        *(f4*)rp = v;
      }
  }
  __syncthreads();
  {
    int e = tid >> 2, c = tid & 3;
    if (e < ne) {
      float* mrow = msg + (size_t)(et + e) * MS;
#pragma unroll
      for (int u = 0; u < 3; ++u) {
        int o0 = c * 12 + u * 4;
        f4 v0 = *(f4*)&red[(size_t)e * 52 + o0];
        f4 v1 = *(f4*)&red[((size_t)(64 + e)) * 52 + o0];
        f4 s = v0 + v1;
        *(f4*)(mrow + o0) = s;   // cols >= 42 are pad; node kernel ignores
      }
    }
  }
#undef COMPUTE
}

// ---------------------------------------------------------------------------
// Node update with fused CSR aggregation:
// aggr = sum over msg rows [rs[n], rs[n+1]); m = relu(aggr + out + conv_bias);
// out_new = concat([m, out]) @ msg_w + msg_b;  last step: d_out = out_new + n_feat
// CSR gather is 4-wide with clamped indices so 4 independent loads are in
// flight per iteration (serial dependent loads were the latency bottleneck).
// ---------------------------------------------------------------------------
__global__ void k_node_update(const float* __restrict__ msg, const int* __restrict__ rs,
                              const float* __restrict__ outp,
                              const float* __restrict__ cb, const float* __restrict__ mw,
                              const float* __restrict__ mb, float* __restrict__ newout,
                              const float* __restrict__ nf, void* __restrict__ fout,
                              int last, const int* __restrict__ flag) {
  int gid = blockIdx.x * blockDim.x + threadIdx.x;
  int n = gid >> 6, lane = gid & 63;
  if (n >= NN) return;
  float ov = (lane < D) ? outp[(size_t)n * D + lane] : 0.f;
  float av = 0.f;
  int r0 = rs[n], r1 = rs[n + 1];
  if (lane < D && r0 < r1) {
    float a0 = 0.f, a1 = 0.f, a2 = 0.f, a3 = 0.f;
    for (int r = r0; r < r1; r += 4) {
      int i1 = (r + 1 < r1) ? r + 1 : r;
      int i2 = (r + 2 < r1) ? r + 2 : r;
      int i3 = (r + 3 < r1) ? r + 3 : r;
      float v0 = msg[(size_t)r  * MS + lane];
      float v1 = msg[(size_t)i1 * MS + lane];
      float v2 = msg[(size_t)i2 * MS + lane];
      float v3 = msg[(size_t)i3 * MS + lane];
      a0 += v0;
      a1 += (r + 1 < r1) ? v1 : 0.f;
      a2 += (r + 2 < r1) ? v2 : 0.f;
      a3 += (r + 3 < r1) ? v3 : 0.f;
    }
    av = (a0 + a1) + (a2 + a3);
  }
  float mv = 0.f;
  if (lane < D) mv = fmaxf(av + ov + cb[lane], 0.f);
  if (lane < D) {
    float acc = mb[lane];
    for (int i = 0; i < D; ++i)
      acc += __shfl(mv, i, 64) * mw[i * D + lane];
    for (int i = 0; i < D; ++i)
      acc += __shfl(ov, i, 64) * mw[(D + i) * D + lane];
    size_t idx = (size_t)n * D + lane;
    if (last) {
      float res = acc + nf[idx];
      if (flag[0]) ((u16*)fout)[idx] = f2bf(res);
      else         ((float*)fout)[idx] = res;
    } else {
      newout[idx] = acc;
    }
  }
}

// ---------------------------------------------------------------------------
extern "C" void kernel_launch(void* const* d_in, const int* in_sizes, int n_in,
                              void* d_out, int out_size, void* d_ws, size_t ws_size,
                              hipStream_t stream) {
  (void)in_sizes; (void)n_in; (void)out_size; (void)ws_size;
  const void* nf   = d_in[0];
  const void* ef   = d_in[1];
  const int*  srcI = (const int*)d_in[2];
  const int*  dstI = (const int*)d_in[3];
  const void* l0w = d_in[4];  const void* l0b = d_in[5];
  const void* e1w = d_in[6];  const void* e1b = d_in[7];
  const void* e2w = d_in[8];  const void* e2b = d_in[9];
  const void* cbI = d_in[10]; const void* mwI = d_in[11]; const void* mbI = d_in[12];

  char* ws = (char*)d_ws;
  size_t off = 0;
  auto alloc = [&](size_t bytes) -> void* {
    void* p = ws + off;
    off = (off + bytes + 255) & ~(size_t)255;
    return p;
  };

  int*   flag  = (int*)alloc(4);
  float* c_nf  = (float*)alloc((size_t)NN * D * 4);
  float* c_ef  = (float*)alloc((size_t)NE * 10 * 4);
  float* c_l0w = (float*)alloc(D * D * 4);
  float* c_l0b = (float*)alloc(D * 4);
  float* c_e1w = (float*)alloc(10 * EH * 4);
  float* c_e1b = (float*)alloc(EH * 4);
  float* c_e2w = (float*)alloc((size_t)EH * DD * 4);
  float* c_e2b = (float*)alloc(DD * 4);
  float* c_cb  = (float*)alloc(D * 4);
  float* c_mw  = (float*)alloc(2 * D * D * 4);
  float* c_mb  = (float*)alloc(D * 4);
  float* out_a = (float*)alloc((size_t)NN * D * 4);
  float* out_b = (float*)alloc((size_t)NN * D * 4);
  u16*   hbf   = (u16*)alloc((size_t)NE * EH * 2);
  u16*   Ap    = (u16*)alloc((size_t)D * 4 * 3 * 64 * 8 * 2);
  u16*   b2p   = (u16*)alloc((size_t)2 * 3 * 64 * 8 * 2);
  int*   cnt    = (int*)alloc((size_t)NN * 4);
  int*   loc    = (int*)alloc((size_t)NN * 4);
  int*   part   = (int*)alloc((size_t)SCAN_NB * 4);
  int*   rowst  = (int*)alloc((size_t)(NN + 1) * 4);
  int*   cursor = (int*)alloc((size_t)NN * 4);
  int*   rank   = (int*)alloc((size_t)NE * 4);
  int*   srcS   = (int*)alloc((size_t)NE * 4);
  float* msg    = (float*)alloc((size_t)NE * MS * 4);

  // dtype probe + canonicalization to fp32
  k_detect<<<1, 256, 0, stream>>>((const u32*)nf, flag);
  auto cvt = [&](const void* s, float* dPtr, int count) {
    k_cvt<<<(count + 255) / 256, 256, 0, stream>>>(s, dPtr, count, flag);
  };
  cvt(nf,  c_nf,  NN * D);
  cvt(ef,  c_ef,  NE * 10);
  cvt(l0w, c_l0w, D * D);
  cvt(l0b, c_l0b, D);
  cvt(e1w, c_e1w, 10 * EH);
  cvt(e1b, c_e1b, EH);
  cvt(e2w, c_e2w, EH * DD);
  cvt(e2b, c_e2b, DD);
  cvt(cbI, c_cb,  D);
  cvt(mwI, c_mw,  2 * D * D);
  cvt(mbI, c_mb,  D);

  // CSR build (dst constant across steps — once per launch)
  (void)hipMemsetAsync(cnt, 0, (size_t)NN * 4, stream);
  k_hist<<<(NE + 255) / 256, 256, 0, stream>>>(dstI, cnt);
  k_scanA<<<SCAN_NB, 256, 0, stream>>>(cnt, loc, part);
  k_scanB<<<1, 256, 0, stream>>>(part);
  k_scanC<<<SCAN_NB, 256, 0, stream>>>(loc, part, rowst);
  (void)hipMemcpyAsync(cursor, rowst, (size_t)NN * 4, hipMemcpyDeviceToDevice, stream);
  k_rank<<<(NE + 255) / 256, 256, 0, stream>>>(dstI, srcI, cursor, rank, srcS);

  // node init + edge network (dst-sorted) + fragment packing
  k_lin0<<<(NN * 64 + 255) / 256, 256, 0, stream>>>(c_nf, c_l0w, c_l0b, out_a);
  k_en1<<<(NE * 128 + 255) / 256, 256, 0, stream>>>(c_ef, c_e1w, c_e1b, rank, hbf);
  k_packA<<<(D * 4 * 3 * 64 * 8 + 255) / 256, 256, 0, stream>>>(c_e2w, Ap);
  k_packB2<<<(2 * 3 * 64 * 8 + 255) / 256, 256, 0, stream>>>(c_e2b, b2p);

  int nblk = (NE + 63) / 64;
  float* cur = out_a;
  float* nxt = out_b;
  for (int s = 0; s < STEPS; ++s) {
    k_edge_mfma<<<nblk, 256, 0, stream>>>(cur, hbf, Ap, b2p, srcS, msg);
    int last = (s == STEPS - 1) ? 1 : 0;
    k_node_update<<<(NN * 64 + 255) / 256, 256, 0, stream>>>(
        msg, rowst, cur, c_cb, c_mw, c_mb, nxt, c_nf, d_out, last, flag);
    float* t = cur; cur = nxt; nxt = t;
  }
}